// Round 7
// baseline (474.978 us; speedup 1.0000x reference)
//
#include <hip/hip_runtime.h>

#define NN 100000
#define NE 1000000
#define NBLK_SCAN 391   // ceil(NN/256)

typedef float f4 __attribute__((ext_vector_type(4)));
typedef float f2 __attribute__((ext_vector_type(2)));
typedef _Float16 h8 __attribute__((ext_vector_type(8)));

__device__ __forceinline__ float silu(float v) {
    return v / (1.0f + __expf(-v));
}

// ws layout (float units)
#define O_SUMS   0            // 6,400,000 f (NN*64)
#define O_CNT    6400000      // 100,000 i
#define O_OFF    6500000      // 100,000 i
#define O_BSUM   6600000      // 512 i
#define O_PERM   6600512      // 1,000,000 i
#define O_XA     7600512      // 3,200,000 f (6.4M fp16)
#define O_XB     10800512     // 3,200,000 f
#define O_W3W    14000512     // 8,320 f (65x128, row 64 = b3@Wout)
#define O_W2T    14008832     // 2,048 f (64x64 fp16 W2^T)
#define O_W1TH   14010880     // 8,192 f (128x128 fp16: W1a^T | W1b^T, hi)
#define O_W1TR   14019072     // 8,192 f (lo residual)          end 14,027,264 f = 56.1 MB

#define HIST_B  3907
#define W3W_B   33
#define PREP0_B (HIST_B + W3W_B + 1 + 8)   // 3949
#define NPRE_B  1563                        // 64 nodes/block
#define MID_B   (NPRE_B + NBLK_SCAN)        // 1954

// ==== prep0: histogram | W3W = W3@Wout | W2^T fp16 | W1^T fp16 (hi+residual) ====
__global__ __launch_bounds__(256) void k_prep0(
    const int* __restrict__ tj,
    const float* __restrict__ W1, const float* __restrict__ W2,
    const float* __restrict__ W3, const float* __restrict__ b3,
    const float* __restrict__ Wout,
    int* __restrict__ C, float* __restrict__ W3W, _Float16* __restrict__ W2t,
    _Float16* __restrict__ W1th, _Float16* __restrict__ W1tr) {
    const int b = blockIdx.x;
    const int t = threadIdx.x;
    if (b < HIST_B) {
        int e = b * 256 + t;
        if (e < NE) atomicAdd(&C[__builtin_nontemporal_load(tj + e)], 1);
    } else if (b < HIST_B + W3W_B) {
        const int row = (b - HIST_B) * 2 + (t >> 7);
        const int c = t & 127;
        if (row < 65) {
            const float* arow = (row < 64) ? (W3 + row * 128) : b3;
            float acc = 0.f;
            for (int d = 0; d < 128; ++d) acc += arow[d] * Wout[d * 128 + c];
            W3W[row * 128 + c] = acc;
        }
    } else if (b < HIST_B + W3W_B + 1) {
        // W2t[n][k] = W2[k][n] fp16
#pragma unroll
        for (int u = 0; u < 16; ++u) {
            const int idx = t * 16 + u;
            const int n = idx >> 6, k = idx & 63;
            W2t[idx] = (_Float16)W2[k * 64 + n];
        }
    } else {
        // W1t[n'][k], n' in [0,128): 0..63 -> W1a cols, 64..127 -> W1b cols
        const int b0 = b - (HIST_B + W3W_B + 1);   // 0..7
#pragma unroll
        for (int u = 0; u < 8; ++u) {
            const int idx = b0 * 2048 + t * 8 + u;   // 0..16383
            const int np = idx >> 7, k = idx & 127;
            const float wfull = W1[(k + ((np >= 64) ? 128 : 0)) * 64 + (np & 63)];
            const _Float16 wh = (_Float16)wfull;
            W1th[idx] = wh;
            W1tr[idx] = (_Float16)(wfull - (float)wh);
        }
    }
}

// ==== mid: [nodepre via MFMA, split-fp16] | [zero sums + local scan of C] ====
__global__ __launch_bounds__(256) void k_mid(
    const float* __restrict__ x,
    const _Float16* __restrict__ W1th, const _Float16* __restrict__ W1tr,
    _Float16* __restrict__ XA, _Float16* __restrict__ XB,
    const int* __restrict__ C, float* __restrict__ sums,
    int* __restrict__ offv, int* __restrict__ Bsum) {
    __shared__ _Float16 XOUT[2][64][72];
    __shared__ int s[256];
    const int b = blockIdx.x;
    const int t = threadIdx.x;
    if (b < NPRE_B) {
        // ---- XA = x@W1a, XB = x@W1b via mfma_f32_16x16x32_f16, 64 nodes/block ----
        // error-free fp16 split: x = xh + xr, W = Wh + Wr; acc += xh*Wh + xr*Wh + xh*Wr
        const int n0 = b * 64;
        const int w = t >> 6;
        const int lane = t & 63;
        const int r15 = lane & 15, blk = lane >> 4;
        const int nodeRow = n0 + w * 16 + r15;
        const bool rowOK = nodeRow < NN;
        f4 accA[4], accB[4];
#pragma unroll
        for (int n = 0; n < 4; ++n) {
            accA[n] = (f4){0.f, 0.f, 0.f, 0.f};
            accB[n] = (f4){0.f, 0.f, 0.f, 0.f};
        }
#pragma unroll
        for (int kk = 0; kk < 4; ++kk) {
            f4 x0 = (f4){0.f, 0.f, 0.f, 0.f}, x1 = x0;
            if (rowOK) {
                const f4* xp = (const f4*)(x + (size_t)nodeRow * 128 + kk * 32 + blk * 8);
                x0 = xp[0];
                x1 = xp[1];
            }
            h8 xh, xr;
#pragma unroll
            for (int n = 0; n < 4; ++n) {
                xh[n] = (_Float16)x0[n];
                xr[n] = (_Float16)(x0[n] - (float)xh[n]);
                xh[4 + n] = (_Float16)x1[n];
                xr[4 + n] = (_Float16)(x1[n] - (float)xh[4 + n]);
            }
#pragma unroll
            for (int ncol = 0; ncol < 4; ++ncol) {
                const int nA = ncol * 16 + r15;
                const int koff = kk * 32 + blk * 8;
                h8 whA = *(const h8*)(W1th + nA * 128 + koff);
                h8 wrA = *(const h8*)(W1tr + nA * 128 + koff);
                accA[ncol] = __builtin_amdgcn_mfma_f32_16x16x32_f16(xh, whA, accA[ncol], 0, 0, 0);
                accA[ncol] = __builtin_amdgcn_mfma_f32_16x16x32_f16(xr, whA, accA[ncol], 0, 0, 0);
                accA[ncol] = __builtin_amdgcn_mfma_f32_16x16x32_f16(xh, wrA, accA[ncol], 0, 0, 0);
                h8 whB = *(const h8*)(W1th + (64 + nA) * 128 + koff);
                h8 wrB = *(const h8*)(W1tr + (64 + nA) * 128 + koff);
                accB[ncol] = __builtin_amdgcn_mfma_f32_16x16x32_f16(xh, whB, accB[ncol], 0, 0, 0);
                accB[ncol] = __builtin_amdgcn_mfma_f32_16x16x32_f16(xr, whB, accB[ncol], 0, 0, 0);
                accB[ncol] = __builtin_amdgcn_mfma_f32_16x16x32_f16(xh, wrB, accB[ncol], 0, 0, 0);
            }
        }
        // repack via LDS (D layout: row = blk*4+reg, col = ncol*16+r15)
#pragma unroll
        for (int ncol = 0; ncol < 4; ++ncol)
#pragma unroll
            for (int reg = 0; reg < 4; ++reg) {
                const int row = w * 16 + blk * 4 + reg;
                XOUT[0][row][ncol * 16 + r15] = (_Float16)accA[ncol][reg];
                XOUT[1][row][ncol * 16 + r15] = (_Float16)accB[ncol][reg];
            }
        __syncthreads();
#pragma unroll
        for (int u = 0; u < 4; ++u) {
            const int idx = t + 256 * u;        // 0..1023
            const int mat = idx >> 9;
            const int row = (idx >> 3) & 63;
            const int c8 = idx & 7;
            const int grow = n0 + row;
            if (grow < NN) {
                _Float16* dst = (mat ? XB : XA) + (size_t)grow * 64 + c8 * 8;
                *(h8*)dst = *(const h8*)&XOUT[mat][row][c8 * 8];
            }
        }
    } else {
        // ---- zero a slice of sums, then local exclusive scan of C ----
        const int sb = b - NPRE_B;
        {
            f4* sz = (f4*)sums + (size_t)sb * 4096;
            const int cnt4 = min(4096, 1600000 - sb * 4096);
            for (int u = t; u < cnt4; u += 256) sz[u] = (f4){0.f, 0.f, 0.f, 0.f};
        }
        const int gid = sb * 256 + t;
        const int v = (gid < NN) ? C[gid] : 0;
        s[t] = v;
        __syncthreads();
        for (int off = 1; off < 256; off <<= 1) {
            int add = (t >= off) ? s[t - off] : 0;
            __syncthreads();
            s[t] += add;
            __syncthreads();
        }
        if (gid < NN) offv[gid] = s[t] - v;
        if (t == 255) Bsum[sb] = s[255];
    }
}

// ==== scatter (with fused scan of Bsum): perm[p] = e ====
__global__ __launch_bounds__(256) void k_scatter(const int* __restrict__ tj,
                                                 const int* __restrict__ Bsum,
                                                 int* __restrict__ offv,
                                                 int* __restrict__ perm) {
    __shared__ int BpreS[NBLK_SCAN];
    const int t = threadIdx.x;
    const int w = t >> 6, lane = t & 63;
    if (w == 0) {
        int carry = 0;
        for (int base = 0; base < NBLK_SCAN; base += 64) {
            const int idx = base + lane;
            const int orig = (idx < NBLK_SCAN) ? Bsum[idx] : 0;
            int v = orig;
#pragma unroll
            for (int off = 1; off < 64; off <<= 1) {
                int u = __shfl_up(v, off, 64);
                if (lane >= off) v += u;
            }
            if (idx < NBLK_SCAN) BpreS[idx] = carry + v - orig;
            carry += __shfl(v, 63, 64);
        }
    }
    __syncthreads();
    const int e = blockIdx.x * 256 + t;
    if (e < NE) {
        const int j = __builtin_nontemporal_load(tj + e);
        const int p = BpreS[j >> 8] + atomicAdd(&offv[j], 1);
        perm[p] = e;
    }
}

// ==== edge kernel: h1 (VALU) -> h2 (MFMA fp16) -> segment-reduce by j ====
__global__ __launch_bounds__(256, 8) void k_edge(
    const int* __restrict__ ti, const int* __restrict__ tj, const int* __restrict__ tk,
    const int* __restrict__ perm, const float* __restrict__ attr,
    const _Float16* __restrict__ XA, const _Float16* __restrict__ XB,
    const float* __restrict__ W1, const float* __restrict__ b1,
    const _Float16* __restrict__ W2t, const float* __restrict__ b2,
    float* __restrict__ sums) {
    __shared__ __align__(16) char SBraw[64 * 68 * 4];  // M[64][68] f32; H1h[64][72] fp16
    __shared__ int JL[64];
    __shared__ int RS[66];
    __shared__ int nruns_s;

    _Float16* H1h = (_Float16*)SBraw;   // [64][72]
    float* M = (float*)SBraw;           // [64][68]

    const int t = threadIdx.x;
    const int w = t >> 6;
    const int lane = t & 63;
    const int EB = blockIdx.x * 64;

    // ---- phase 1: h1 = silu(XA[i] + XB[k] + attr@W1c + b1) fp16, 4 thr/edge ----
    {
        const int el = t >> 2;
        const int q = t & 3;
        const int e = __builtin_nontemporal_load(perm + EB + el);
        const int i = __builtin_nontemporal_load(ti + e);
        const int k = __builtin_nontemporal_load(tk + e);
        if (q == 0) JL[el] = __builtin_nontemporal_load(tj + e);
        f2 at = __builtin_nontemporal_load((const f2*)attr + e);
        const _Float16* xa = XA + (size_t)i * 64 + q * 16;
        const _Float16* xb = XB + (size_t)k * 64 + q * 16;
        h8 va0 = ((const h8*)xa)[0], va1 = ((const h8*)xa)[1];
        h8 vb0 = ((const h8*)xb)[0], vb1 = ((const h8*)xb)[1];
        float fa[16], fb[16];
#pragma unroll
        for (int n = 0; n < 8; ++n) {
            fa[n] = (float)va0[n]; fa[8 + n] = (float)va1[n];
            fb[n] = (float)vb0[n]; fb[8 + n] = (float)vb1[n];
        }
        const float* c0 = W1 + 256 * 64 + q * 16;
        const float* c1 = W1 + 257 * 64 + q * 16;
        const float* bq = b1 + q * 16;
        _Float16 hrow[16];
#pragma unroll
        for (int m4 = 0; m4 < 4; ++m4) {
            f4 vc0 = ((const f4*)c0)[m4];
            f4 vc1 = ((const f4*)c1)[m4];
            f4 vbq = ((const f4*)bq)[m4];
#pragma unroll
            for (int n = 0; n < 4; ++n) {
                const int idx = m4 * 4 + n;
                float pre = fa[idx] + fb[idx] + at[0] * vc0[n] + at[1] * vc1[n] + vbq[n];
                hrow[idx] = (_Float16)silu(pre);
            }
        }
        h8 s0, s1;
#pragma unroll
        for (int n = 0; n < 8; ++n) { s0[n] = hrow[n]; s1[n] = hrow[8 + n]; }
        _Float16* row = H1h + el * 72 + q * 16;
        ((h8*)row)[0] = s0;
        ((h8*)row)[1] = s1;
    }
    __syncthreads();

    // ---- phase 2: H2 = silu(H1 @ W2 + b2) via mfma_f32_16x16x32_f16 ----
    const int r15 = lane & 15;
    const int blk = lane >> 4;
    float h2v[16];
    {
        const _Float16* H1w = H1h + (w * 16) * 72;
        h8 a0 = *(const h8*)(H1w + r15 * 72 + blk * 8);
        h8 a1 = *(const h8*)(H1w + r15 * 72 + 32 + blk * 8);
#pragma unroll
        for (int ncol = 0; ncol < 4; ++ncol) {
            const _Float16* Wn = W2t + (ncol * 16 + r15) * 64 + blk * 8;
            h8 b0 = *(const h8*)(Wn);
            h8 b1v = *(const h8*)(Wn + 32);
            const float bc = b2[ncol * 16 + r15];
            f4 acc = {bc, bc, bc, bc};
            acc = __builtin_amdgcn_mfma_f32_16x16x32_f16(a0, b0, acc, 0, 0, 0);
            acc = __builtin_amdgcn_mfma_f32_16x16x32_f16(a1, b1v, acc, 0, 0, 0);
#pragma unroll
            for (int reg = 0; reg < 4; ++reg) h2v[ncol * 4 + reg] = silu(acc[reg]);
        }
    }
    __syncthreads();

    // ---- phase 3: write H2 to M (f32); wave 0 finds run heads over sorted JL ----
#pragma unroll
    for (int ncol = 0; ncol < 4; ++ncol)
#pragma unroll
        for (int reg = 0; reg < 4; ++reg)
            M[(w * 16 + blk * 4 + reg) * 68 + ncol * 16 + r15] = h2v[ncol * 4 + reg];
    if (t < 64) {
        bool head = (t == 0) || (JL[t] != JL[t - 1]);
        unsigned long long mask = __ballot(head);
        if (head) {
            int rank = __popcll(mask & ((1ull << t) - 1ull));
            RS[rank] = t;
        }
        if (t == 0) {
            int nr = __popcll(mask);
            nruns_s = nr;
            RS[nr] = 64;
        }
    }
    __syncthreads();

    // ---- phase 4: per-run column reduce + one 64-wide atomic row per run ----
    {
        const int col = t & 63;
        const int q4 = t >> 6;
        const int nr = nruns_s;
        for (int rid = q4; rid < nr; rid += 4) {
            const int s0 = RS[rid];
            const int s1 = RS[rid + 1];
            float a = 0.f;
            for (int rr = s0; rr < s1; ++rr) a += M[rr * 68 + col];
            atomicAdd(&sums[(size_t)JL[s0] * 64 + col], a);
        }
    }
}

// ==== out = (sums/max(cnt,1)) @ W3W + [cnt>0]*bout (32 nodes/block) ====
__global__ __launch_bounds__(256) void k_out(const float* __restrict__ sums,
                                             const int* __restrict__ C,
                                             const float* __restrict__ W3W,
                                             float* __restrict__ out) {
    __shared__ float S[32][64];
    __shared__ float bs[32];
    const int t = threadIdx.x;
    const int n0 = blockIdx.x * 32;
    const f4* ss = (const f4*)(sums + (size_t)n0 * 64);
    f4* Ss = (f4*)&S[0][0];
#pragma unroll
    for (int q = 0; q < 2; ++q) {
        const int fidx = t + 256 * q;
        const int row = fidx >> 4;
        const int cn = C[n0 + row];
        const float sc = (cn > 0) ? 1.0f / (float)cn : 0.0f;
        f4 v = ss[fidx];
#pragma unroll
        for (int n = 0; n < 4; ++n) v[n] *= sc;
        Ss[fidx] = v;
    }
    if (t < 32) bs[t] = (C[n0 + t] > 0) ? 1.0f : 0.0f;
    __syncthreads();
    const int w = t >> 6, lane = t & 63;
    const float* bout = W3W + 64 * 128;
    float a0[8], a1[8];
#pragma unroll
    for (int m = 0; m < 8; ++m) { a0[m] = 0.f; a1[m] = 0.f; }
    for (int d = 0; d < 64; ++d) {
        float w0 = W3W[d * 128 + lane];
        float w1 = W3W[d * 128 + 64 + lane];
#pragma unroll
        for (int m = 0; m < 8; ++m) {
            float sv = S[w * 8 + m][d];
            a0[m] += sv * w0;
            a1[m] += sv * w1;
        }
    }
    const float bo0 = bout[lane], bo1 = bout[64 + lane];
#pragma unroll
    for (int m = 0; m < 8; ++m) {
        const int node = n0 + w * 8 + m;
        const float b = bs[w * 8 + m];
        out[(size_t)node * 128 + lane] = a0[m] + b * bo0;
        out[(size_t)node * 128 + 64 + lane] = a1[m] + b * bo1;
    }
}

extern "C" void kernel_launch(void* const* d_in, const int* in_sizes, int n_in,
                              void* d_out, int out_size, void* d_ws, size_t ws_size,
                              hipStream_t stream) {
    const float* x    = (const float*)d_in[0];
    const int*   idx  = (const int*)d_in[1];
    const float* attr = (const float*)d_in[2];
    const float* W1   = (const float*)d_in[3];
    const float* b1   = (const float*)d_in[4];
    const float* W2   = (const float*)d_in[5];
    const float* b2   = (const float*)d_in[6];
    const float* W3   = (const float*)d_in[7];
    const float* b3   = (const float*)d_in[8];
    const float* Wout = (const float*)d_in[9];
    float* out = (float*)d_out;

    const int* ti = idx;
    const int* tj = idx + NE;
    const int* tk = idx + 2 * NE;

    float* ws   = (float*)d_ws;
    float* sums = ws + O_SUMS;
    int*   C    = (int*)(ws + O_CNT);
    int*   offv = (int*)(ws + O_OFF);
    int*   Bsum = (int*)(ws + O_BSUM);
    int*   perm = (int*)(ws + O_PERM);
    _Float16* XA  = (_Float16*)(ws + O_XA);
    _Float16* XB  = (_Float16*)(ws + O_XB);
    float* W3W  = ws + O_W3W;
    _Float16* W2t  = (_Float16*)(ws + O_W2T);
    _Float16* W1th = (_Float16*)(ws + O_W1TH);
    _Float16* W1tr = (_Float16*)(ws + O_W1TR);

    hipMemsetAsync(C, 0, (size_t)NN * sizeof(int), stream);

    hipLaunchKernelGGL(k_prep0,   dim3(PREP0_B), dim3(256), 0, stream,
                       tj, W1, W2, W3, b3, Wout, C, W3W, W2t, W1th, W1tr);
    hipLaunchKernelGGL(k_mid,     dim3(MID_B), dim3(256), 0, stream,
                       x, W1th, W1tr, XA, XB, C, sums, offv, Bsum);
    hipLaunchKernelGGL(k_scatter, dim3(3907), dim3(256), 0, stream, tj, Bsum, offv, perm);
    hipLaunchKernelGGL(k_edge,    dim3(15625), dim3(256), 0, stream,
                       ti, tj, tk, perm, attr, XA, XB, W1, b1, W2t, b2, sums);
    hipLaunchKernelGGL(k_out,     dim3(3125), dim3(256), 0, stream, sums, C, W3W, out);
}

// Round 9
// 401.109 us; speedup vs baseline: 1.1842x; 1.1842x over previous
//
#include <hip/hip_runtime.h>

#define NN 100000
#define NE 1000000
#define NBLK_SCAN 391   // ceil(NN/256)

typedef float f4 __attribute__((ext_vector_type(4)));
typedef float f2 __attribute__((ext_vector_type(2)));
typedef _Float16 h8 __attribute__((ext_vector_type(8)));

__device__ __forceinline__ float silu(float v) {
    return v / (1.0f + __expf(-v));
}

// ws layout (float units)
#define O_SUMS   0            // 6,400,000 f (NN*64)
#define O_CNT    6400000      // 100,000 i
#define O_OFF    6500000      // 100,000 i
#define O_BSUM   6600000      // 512 i
#define O_TJS    6600512      // 1,000,000 i (sorted j per position)
#define O_PL     7600512      // 4,000,000 i (int4 payload {i,k,at0,at1}; byte off %16==0)
#define O_XA     11600512     // 3,200,000 f (6.4M fp16)
#define O_XB     14800512     // 3,200,000 f
#define O_W3W    18000512     // 8,320 f (65x128, row 64 = b3@Wout)
#define O_W2T    18008832     // 2,048 f (64x64 fp16 W2^T)
#define O_W1TH   18010880     // 8,192 f (128x128 fp16: W1a^T | W1b^T, hi)
#define O_W1TR   18019072     // 8,192 f (lo residual)
#define O_W1C16  18027264     // 96 f (192 fp16: c0[64] | c1[64] | b1[64])  end 72.1 MB

#define HIST_B  3907
#define W3W_B   33
#define PREP0_B (HIST_B + W3W_B + 1 + 8)   // 3949
#define NPRE_B  1563                        // 64 nodes/block
#define MID_B   (NPRE_B + NBLK_SCAN)        // 1954
#define EDGE_B1 7813
#define EDGE_B2 7812

// ==== prep0: histogram | W3W = W3@Wout | W2^T,W1c,b1 fp16 | W1^T fp16 split ====
__global__ __launch_bounds__(256) void k_prep0(
    const int* __restrict__ tj,
    const float* __restrict__ W1, const float* __restrict__ b1,
    const float* __restrict__ W2,
    const float* __restrict__ W3, const float* __restrict__ b3,
    const float* __restrict__ Wout,
    int* __restrict__ C, float* __restrict__ W3W, _Float16* __restrict__ W2t,
    _Float16* __restrict__ W1th, _Float16* __restrict__ W1tr,
    _Float16* __restrict__ W1C16) {
    const int b = blockIdx.x;
    const int t = threadIdx.x;
    if (b < HIST_B) {
        int e = b * 256 + t;
        if (e < NE) atomicAdd(&C[tj[e]], 1);
    } else if (b < HIST_B + W3W_B) {
        const int row = (b - HIST_B) * 2 + (t >> 7);
        const int c = t & 127;
        if (row < 65) {
            const float* arow = (row < 64) ? (W3 + row * 128) : b3;
            float acc = 0.f;
            for (int d = 0; d < 128; ++d) acc += arow[d] * Wout[d * 128 + c];
            W3W[row * 128 + c] = acc;
        }
    } else if (b < HIST_B + W3W_B + 1) {
        // W2t[n][k] = W2[k][n] fp16
#pragma unroll
        for (int u = 0; u < 16; ++u) {
            const int idx = t * 16 + u;
            const int n = idx >> 6, k = idx & 63;
            W2t[idx] = (_Float16)W2[k * 64 + n];
        }
        if (t < 64) {
            W1C16[t]        = (_Float16)W1[256 * 64 + t];
            W1C16[64 + t]   = (_Float16)W1[257 * 64 + t];
            W1C16[128 + t]  = (_Float16)b1[t];
        }
    } else {
        // W1t[n'][k], n' in [0,128): 0..63 -> W1a cols, 64..127 -> W1b cols
        const int b0 = b - (HIST_B + W3W_B + 1);   // 0..7
#pragma unroll
        for (int u = 0; u < 8; ++u) {
            const int idx = b0 * 2048 + t * 8 + u;   // 0..16383
            const int np = idx >> 7, k = idx & 127;
            const float wfull = W1[(k + ((np >= 64) ? 128 : 0)) * 64 + (np & 63)];
            const _Float16 wh = (_Float16)wfull;
            W1th[idx] = wh;
            W1tr[idx] = (_Float16)(wfull - (float)wh);
        }
    }
}

// ==== mid: [nodepre via MFMA, split-fp16] | [zero sums + local scan of C] ====
__global__ __launch_bounds__(256) void k_mid(
    const float* __restrict__ x,
    const _Float16* __restrict__ W1th, const _Float16* __restrict__ W1tr,
    _Float16* __restrict__ XA, _Float16* __restrict__ XB,
    const int* __restrict__ C, float* __restrict__ sums,
    int* __restrict__ offv, int* __restrict__ Bsum) {
    __shared__ _Float16 XOUT[2][64][72];
    __shared__ int s[256];
    const int b = blockIdx.x;
    const int t = threadIdx.x;
    if (b < NPRE_B) {
        // error-free fp16 split: x = xh + xr, W = Wh + Wr; acc += xh*Wh + xr*Wh + xh*Wr
        const int n0 = b * 64;
        const int w = t >> 6;
        const int lane = t & 63;
        const int r15 = lane & 15, blk = lane >> 4;
        const int nodeRow = n0 + w * 16 + r15;
        const bool rowOK = nodeRow < NN;
        f4 accA[4], accB[4];
#pragma unroll
        for (int n = 0; n < 4; ++n) {
            accA[n] = (f4){0.f, 0.f, 0.f, 0.f};
            accB[n] = (f4){0.f, 0.f, 0.f, 0.f};
        }
#pragma unroll
        for (int kk = 0; kk < 4; ++kk) {
            f4 x0 = (f4){0.f, 0.f, 0.f, 0.f}, x1 = x0;
            if (rowOK) {
                const f4* xp = (const f4*)(x + (size_t)nodeRow * 128 + kk * 32 + blk * 8);
                x0 = xp[0];
                x1 = xp[1];
            }
            h8 xh, xr;
#pragma unroll
            for (int n = 0; n < 4; ++n) {
                xh[n] = (_Float16)x0[n];
                xr[n] = (_Float16)(x0[n] - (float)xh[n]);
                xh[4 + n] = (_Float16)x1[n];
                xr[4 + n] = (_Float16)(x1[n] - (float)xh[4 + n]);
            }
#pragma unroll
            for (int ncol = 0; ncol < 4; ++ncol) {
                const int nA = ncol * 16 + r15;
                const int koff = kk * 32 + blk * 8;
                h8 whA = *(const h8*)(W1th + nA * 128 + koff);
                h8 wrA = *(const h8*)(W1tr + nA * 128 + koff);
                accA[ncol] = __builtin_amdgcn_mfma_f32_16x16x32_f16(xh, whA, accA[ncol], 0, 0, 0);
                accA[ncol] = __builtin_amdgcn_mfma_f32_16x16x32_f16(xr, whA, accA[ncol], 0, 0, 0);
                accA[ncol] = __builtin_amdgcn_mfma_f32_16x16x32_f16(xh, wrA, accA[ncol], 0, 0, 0);
                h8 whB = *(const h8*)(W1th + (64 + nA) * 128 + koff);
                h8 wrB = *(const h8*)(W1tr + (64 + nA) * 128 + koff);
                accB[ncol] = __builtin_amdgcn_mfma_f32_16x16x32_f16(xh, whB, accB[ncol], 0, 0, 0);
                accB[ncol] = __builtin_amdgcn_mfma_f32_16x16x32_f16(xr, whB, accB[ncol], 0, 0, 0);
                accB[ncol] = __builtin_amdgcn_mfma_f32_16x16x32_f16(xh, wrB, accB[ncol], 0, 0, 0);
            }
        }
        // repack via LDS (D layout: row = blk*4+reg, col = ncol*16+r15)
#pragma unroll
        for (int ncol = 0; ncol < 4; ++ncol)
#pragma unroll
            for (int reg = 0; reg < 4; ++reg) {
                const int row = w * 16 + blk * 4 + reg;
                XOUT[0][row][ncol * 16 + r15] = (_Float16)accA[ncol][reg];
                XOUT[1][row][ncol * 16 + r15] = (_Float16)accB[ncol][reg];
            }
        __syncthreads();
#pragma unroll
        for (int u = 0; u < 4; ++u) {
            const int idx = t + 256 * u;        // 0..1023
            const int mat = idx >> 9;
            const int row = (idx >> 3) & 63;
            const int c8 = idx & 7;
            const int grow = n0 + row;
            if (grow < NN) {
                _Float16* dst = (mat ? XB : XA) + (size_t)grow * 64 + c8 * 8;
                *(h8*)dst = *(const h8*)&XOUT[mat][row][c8 * 8];
            }
        }
    } else {
        // ---- zero a slice of sums, then local exclusive scan of C ----
        const int sb = b - NPRE_B;
        {
            f4* sz = (f4*)sums + (size_t)sb * 4096;
            const int cnt4 = min(4096, 1600000 - sb * 4096);
            for (int u = t; u < cnt4; u += 256) sz[u] = (f4){0.f, 0.f, 0.f, 0.f};
        }
        const int gid = sb * 256 + t;
        const int v = (gid < NN) ? C[gid] : 0;
        s[t] = v;
        __syncthreads();
        for (int off = 1; off < 256; off <<= 1) {
            int add = (t >= off) ? s[t - off] : 0;
            __syncthreads();
            s[t] += add;
            __syncthreads();
        }
        if (gid < NN) offv[gid] = s[t] - v;
        if (t == 255) Bsum[sb] = s[255];
    }
}

// ==== scatter (fused Bsum scan): write permuted payload streams ====
__global__ __launch_bounds__(256) void k_scatter(
    const int* __restrict__ ti, const int* __restrict__ tj, const int* __restrict__ tk,
    const float* __restrict__ attr,
    const int* __restrict__ Bsum, int* __restrict__ offv,
    int* __restrict__ tjs, int4* __restrict__ PL4) {
    __shared__ int BpreS[NBLK_SCAN];
    const int t = threadIdx.x;
    const int w = t >> 6, lane = t & 63;
    if (w == 0) {
        int carry = 0;
        for (int base = 0; base < NBLK_SCAN; base += 64) {
            const int idx = base + lane;
            const int orig = (idx < NBLK_SCAN) ? Bsum[idx] : 0;
            int v = orig;
#pragma unroll
            for (int off = 1; off < 64; off <<= 1) {
                int u = __shfl_up(v, off, 64);
                if (lane >= off) v += u;
            }
            if (idx < NBLK_SCAN) BpreS[idx] = carry + v - orig;
            carry += __shfl(v, 63, 64);
        }
    }
    __syncthreads();
    const int e = blockIdx.x * 256 + t;
    if (e < NE) {
        const int j = tj[e];
        const f2 at = ((const f2*)attr)[e];
        const int p = BpreS[j >> 8] + atomicAdd(&offv[j], 1);
        tjs[p] = j;
        PL4[p] = (int4){ti[e], tk[e], __float_as_int(at[0]), __float_as_int(at[1])};
    }
}

// ==== edge kernel: h1 (VALU) -> h2 (MFMA fp16) -> segment-reduce by j ====
__global__ __launch_bounds__(256, 8) void k_edge(
    const int* __restrict__ tjs, const int4* __restrict__ PL4,
    const _Float16* __restrict__ XA, const _Float16* __restrict__ XB,
    const _Float16* __restrict__ W1C16,
    const _Float16* __restrict__ W2t, const float* __restrict__ b2,
    float* __restrict__ sums, int blk0) {
    __shared__ __align__(16) char SBraw[64 * 68 * 4];  // M[64][68] f32; H1h[64][72] fp16
    __shared__ int JL[64];
    __shared__ int RS[66];
    __shared__ int nruns_s;

    _Float16* H1h = (_Float16*)SBraw;   // [64][72]
    float* M = (float*)SBraw;           // [64][68]

    const int t = threadIdx.x;
    const int w = t >> 6;
    const int lane = t & 63;
    const int EB = (blk0 + blockIdx.x) * 64;

    // ---- phase 1: h1 = silu(XA[i] + XB[k] + attr@W1c + b1) fp16, 4 thr/edge ----
    {
        const int el = t >> 2;
        const int q = t & 3;
        const int4 pl = PL4[EB + el];
        const int i = pl.x;
        const int k = pl.y;
        if (q == 0) JL[el] = tjs[EB + el];
        const float at0 = __int_as_float(pl.z);
        const float at1 = __int_as_float(pl.w);
        const _Float16* xa = XA + (size_t)i * 64 + q * 16;
        const _Float16* xb = XB + (size_t)k * 64 + q * 16;
        h8 va0 = ((const h8*)xa)[0], va1 = ((const h8*)xa)[1];
        h8 vb0 = ((const h8*)xb)[0], vb1 = ((const h8*)xb)[1];
        const _Float16* c0p = W1C16 + q * 16;
        const _Float16* c1p = W1C16 + 64 + q * 16;
        const _Float16* bqp = W1C16 + 128 + q * 16;
        h8 c00 = ((const h8*)c0p)[0], c01 = ((const h8*)c0p)[1];
        h8 c10 = ((const h8*)c1p)[0], c11 = ((const h8*)c1p)[1];
        h8 bq0 = ((const h8*)bqp)[0], bq1 = ((const h8*)bqp)[1];
        _Float16 hrow[16];
#pragma unroll
        for (int n = 0; n < 8; ++n) {
            float pre0 = (float)va0[n] + (float)vb0[n]
                       + at0 * (float)c00[n] + at1 * (float)c10[n] + (float)bq0[n];
            float pre1 = (float)va1[n] + (float)vb1[n]
                       + at0 * (float)c01[n] + at1 * (float)c11[n] + (float)bq1[n];
            hrow[n] = (_Float16)silu(pre0);
            hrow[8 + n] = (_Float16)silu(pre1);
        }
        h8 s0, s1;
#pragma unroll
        for (int n = 0; n < 8; ++n) { s0[n] = hrow[n]; s1[n] = hrow[8 + n]; }
        _Float16* row = H1h + el * 72 + q * 16;
        ((h8*)row)[0] = s0;
        ((h8*)row)[1] = s1;
    }
    __syncthreads();

    // ---- phase 2: H2 = silu(H1 @ W2 + b2) via mfma_f32_16x16x32_f16 ----
    const int r15 = lane & 15;
    const int blk = lane >> 4;
    float h2v[16];
    {
        const _Float16* H1w = H1h + (w * 16) * 72;
        h8 a0 = *(const h8*)(H1w + r15 * 72 + blk * 8);
        h8 a1 = *(const h8*)(H1w + r15 * 72 + 32 + blk * 8);
#pragma unroll
        for (int ncol = 0; ncol < 4; ++ncol) {
            const _Float16* Wn = W2t + (ncol * 16 + r15) * 64 + blk * 8;
            h8 b0 = *(const h8*)(Wn);
            h8 b1v = *(const h8*)(Wn + 32);
            const float bc = b2[ncol * 16 + r15];
            f4 acc = {bc, bc, bc, bc};
            acc = __builtin_amdgcn_mfma_f32_16x16x32_f16(a0, b0, acc, 0, 0, 0);
            acc = __builtin_amdgcn_mfma_f32_16x16x32_f16(a1, b1v, acc, 0, 0, 0);
#pragma unroll
            for (int reg = 0; reg < 4; ++reg) h2v[ncol * 4 + reg] = silu(acc[reg]);
        }
    }
    __syncthreads();

    // ---- phase 3: write H2 to M (f32); wave 0 finds run heads over sorted JL ----
#pragma unroll
    for (int ncol = 0; ncol < 4; ++ncol)
#pragma unroll
        for (int reg = 0; reg < 4; ++reg)
            M[(w * 16 + blk * 4 + reg) * 68 + ncol * 16 + r15] = h2v[ncol * 4 + reg];
    if (t < 64) {
        bool head = (t == 0) || (JL[t] != JL[t - 1]);
        unsigned long long mask = __ballot(head);
        if (head) {
            int rank = __popcll(mask & ((1ull << t) - 1ull));
            RS[rank] = t;
        }
        if (t == 0) {
            int nr = __popcll(mask);
            nruns_s = nr;
            RS[nr] = 64;
        }
    }
    __syncthreads();

    // ---- phase 4: per-run column reduce + one 64-wide atomic row per run ----
    {
        const int col = t & 63;
        const int q4 = t >> 6;
        const int nr = nruns_s;
        for (int rid = q4; rid < nr; rid += 4) {
            const int s0 = RS[rid];
            const int s1 = RS[rid + 1];
            float a = 0.f;
            for (int rr = s0; rr < s1; ++rr) a += M[rr * 68 + col];
            atomicAdd(&sums[(size_t)JL[s0] * 64 + col], a);
        }
    }
}

// ==== out = (sums/max(cnt,1)) @ W3W + [cnt>0]*bout (32 nodes/block) ====
__global__ __launch_bounds__(256) void k_out(const float* __restrict__ sums,
                                             const int* __restrict__ C,
                                             const float* __restrict__ W3W,
                                             float* __restrict__ out) {
    __shared__ float S[32][64];
    __shared__ float bs[32];
    const int t = threadIdx.x;
    const int n0 = blockIdx.x * 32;
    const f4* ss = (const f4*)(sums + (size_t)n0 * 64);
    f4* Ss = (f4*)&S[0][0];
#pragma unroll
    for (int q = 0; q < 2; ++q) {
        const int fidx = t + 256 * q;
        const int row = fidx >> 4;
        const int cn = C[n0 + row];
        const float sc = (cn > 0) ? 1.0f / (float)cn : 0.0f;
        f4 v = ss[fidx];
#pragma unroll
        for (int n = 0; n < 4; ++n) v[n] *= sc;
        Ss[fidx] = v;
    }
    if (t < 32) bs[t] = (C[n0 + t] > 0) ? 1.0f : 0.0f;
    __syncthreads();
    const int w = t >> 6, lane = t & 63;
    const float* bout = W3W + 64 * 128;
    float a0[8], a1[8];
#pragma unroll
    for (int m = 0; m < 8; ++m) { a0[m] = 0.f; a1[m] = 0.f; }
    for (int d = 0; d < 64; ++d) {
        float w0 = W3W[d * 128 + lane];
        float w1 = W3W[d * 128 + 64 + lane];
#pragma unroll
        for (int m = 0; m < 8; ++m) {
            float sv = S[w * 8 + m][d];
            a0[m] += sv * w0;
            a1[m] += sv * w1;
        }
    }
    const float bo0 = bout[lane], bo1 = bout[64 + lane];
#pragma unroll
    for (int m = 0; m < 8; ++m) {
        const int node = n0 + w * 8 + m;
        const float b = bs[w * 8 + m];
        out[(size_t)node * 128 + lane] = a0[m] + b * bo0;
        out[(size_t)node * 128 + 64 + lane] = a1[m] + b * bo1;
    }
}

extern "C" void kernel_launch(void* const* d_in, const int* in_sizes, int n_in,
                              void* d_out, int out_size, void* d_ws, size_t ws_size,
                              hipStream_t stream) {
    const float* x    = (const float*)d_in[0];
    const int*   idx  = (const int*)d_in[1];
    const float* attr = (const float*)d_in[2];
    const float* W1   = (const float*)d_in[3];
    const float* b1   = (const float*)d_in[4];
    const float* W2   = (const float*)d_in[5];
    const float* b2   = (const float*)d_in[6];
    const float* W3   = (const float*)d_in[7];
    const float* b3   = (const float*)d_in[8];
    const float* Wout = (const float*)d_in[9];
    float* out = (float*)d_out;

    const int* ti = idx;
    const int* tj = idx + NE;
    const int* tk = idx + 2 * NE;

    float* ws   = (float*)d_ws;
    float* sums = ws + O_SUMS;
    int*   C    = (int*)(ws + O_CNT);
    int*   offv = (int*)(ws + O_OFF);
    int*   Bsum = (int*)(ws + O_BSUM);
    int*   tjs  = (int*)(ws + O_TJS);
    int4*  PL4  = (int4*)(ws + O_PL);
    _Float16* XA  = (_Float16*)(ws + O_XA);
    _Float16* XB  = (_Float16*)(ws + O_XB);
    float* W3W  = ws + O_W3W;
    _Float16* W2t   = (_Float16*)(ws + O_W2T);
    _Float16* W1th  = (_Float16*)(ws + O_W1TH);
    _Float16* W1tr  = (_Float16*)(ws + O_W1TR);
    _Float16* W1C16 = (_Float16*)(ws + O_W1C16);

    hipMemsetAsync(C, 0, (size_t)NN * sizeof(int), stream);

    hipLaunchKernelGGL(k_prep0,   dim3(PREP0_B), dim3(256), 0, stream,
                       tj, W1, b1, W2, W3, b3, Wout, C, W3W, W2t, W1th, W1tr, W1C16);
    hipLaunchKernelGGL(k_mid,     dim3(MID_B), dim3(256), 0, stream,
                       x, W1th, W1tr, XA, XB, C, sums, offv, Bsum);
    hipLaunchKernelGGL(k_scatter, dim3(3907), dim3(256), 0, stream,
                       ti, tj, tk, attr, Bsum, offv, tjs, PL4);
    hipLaunchKernelGGL(k_edge,    dim3(EDGE_B1), dim3(256), 0, stream,
                       tjs, PL4, XA, XB, W1C16, W2t, b2, sums, 0);
    hipLaunchKernelGGL(k_edge,    dim3(EDGE_B2), dim3(256), 0, stream,
                       tjs, PL4, XA, XB, W1C16, W2t, b2, sums, EDGE_B1);
    hipLaunchKernelGGL(k_out,     dim3(3125), dim3(256), 0, stream, sums, C, W3W, out);
}

// Round 10
// 398.586 us; speedup vs baseline: 1.1917x; 1.0063x over previous
//
#include <hip/hip_runtime.h>

#define NN 100000
#define NE 1000000
#define NBLK_SCAN 391   // ceil(NN/256)

typedef float f4 __attribute__((ext_vector_type(4)));
typedef float f2 __attribute__((ext_vector_type(2)));
typedef _Float16 h8 __attribute__((ext_vector_type(8)));

__device__ __forceinline__ float silu(float v) {
    return v / (1.0f + __expf(-v));
}

__device__ __forceinline__ unsigned pack_f16x2(float a, float b) {
    unsigned short ua = __builtin_bit_cast(unsigned short, (_Float16)a);
    unsigned short ub = __builtin_bit_cast(unsigned short, (_Float16)b);
    return (unsigned)ua | ((unsigned)ub << 16);
}

// ws layout (float units)
#define O_SUMS   0            // 6,400,000 f (NN*64)
#define O_CNT    6400000      // 100,000 i
#define O_OFF    6500000      // 100,000 i
#define O_BSUM   6600000      // 512 i
#define O_PL     7600512      // 4,000,000 i (int4 {i, k, at_f16x2, j}; 16B aligned)
#define O_XA     11600512     // 3,200,000 f (6.4M fp16)
#define O_XB     14800512     // 3,200,000 f
#define O_W3W    18000512     // 8,320 f (65x128, row 64 = b3@Wout)
#define O_W2T    18008832     // 2,048 f (64x64 fp16 W2^T)
#define O_W1TH   18010880     // 8,192 f (128x128 fp16: W1a^T | W1b^T, hi)
#define O_W1TR   18019072     // 8,192 f (lo residual)
#define O_W1C16  18027264     // 96 f (192 fp16: c0[64] | c1[64] | b1[64])  end 72.1 MB

#define HIST_B4 977                          // 977*1024 >= 1M, 4 edges/thread
#define W3W_B   33
#define PREP0_B (HIST_B4 + W3W_B + 1 + 8)    // 1019
#define NPRE_B  1563                          // 64 nodes/block
#define MID_B   (NPRE_B + NBLK_SCAN)          // 1954
#define SCAT_B  977
#define EDGE_B1 7813
#define EDGE_B2 7812

// ==== prep0: histogram(ILP4) | W3W = W3@Wout | W2^T,W1c,b1 fp16 | W1^T fp16 split ====
__global__ __launch_bounds__(256) void k_prep0(
    const int* __restrict__ tj,
    const float* __restrict__ W1, const float* __restrict__ b1,
    const float* __restrict__ W2,
    const float* __restrict__ W3, const float* __restrict__ b3,
    const float* __restrict__ Wout,
    int* __restrict__ C, float* __restrict__ W3W, _Float16* __restrict__ W2t,
    _Float16* __restrict__ W1th, _Float16* __restrict__ W1tr,
    _Float16* __restrict__ W1C16) {
    const int b = blockIdx.x;
    const int t = threadIdx.x;
    if (b < HIST_B4) {
        const int base = b * 1024 + t;
#pragma unroll
        for (int u = 0; u < 4; ++u) {
            const int e = base + u * 256;
            if (e < NE) atomicAdd(&C[tj[e]], 1);
        }
    } else if (b < HIST_B4 + W3W_B) {
        const int row = (b - HIST_B4) * 2 + (t >> 7);
        const int c = t & 127;
        if (row < 65) {
            const float* arow = (row < 64) ? (W3 + row * 128) : b3;
            float acc = 0.f;
            for (int d = 0; d < 128; ++d) acc += arow[d] * Wout[d * 128 + c];
            W3W[row * 128 + c] = acc;
        }
    } else if (b < HIST_B4 + W3W_B + 1) {
        // W2t[n][k] = W2[k][n] fp16
#pragma unroll
        for (int u = 0; u < 16; ++u) {
            const int idx = t * 16 + u;
            const int n = idx >> 6, k = idx & 63;
            W2t[idx] = (_Float16)W2[k * 64 + n];
        }
        if (t < 64) {
            W1C16[t]        = (_Float16)W1[256 * 64 + t];
            W1C16[64 + t]   = (_Float16)W1[257 * 64 + t];
            W1C16[128 + t]  = (_Float16)b1[t];
        }
    } else {
        // W1t[n'][k], n' in [0,128): 0..63 -> W1a cols, 64..127 -> W1b cols
        const int b0 = b - (HIST_B4 + W3W_B + 1);   // 0..7
#pragma unroll
        for (int u = 0; u < 8; ++u) {
            const int idx = b0 * 2048 + t * 8 + u;   // 0..16383
            const int np = idx >> 7, k = idx & 127;
            const float wfull = W1[(k + ((np >= 64) ? 128 : 0)) * 64 + (np & 63)];
            const _Float16 wh = (_Float16)wfull;
            W1th[idx] = wh;
            W1tr[idx] = (_Float16)(wfull - (float)wh);
        }
    }
}

// ==== mid: [nodepre via MFMA, split-fp16] | [zero sums + local scan of C] ====
__global__ __launch_bounds__(256) void k_mid(
    const float* __restrict__ x,
    const _Float16* __restrict__ W1th, const _Float16* __restrict__ W1tr,
    _Float16* __restrict__ XA, _Float16* __restrict__ XB,
    const int* __restrict__ C, float* __restrict__ sums,
    int* __restrict__ offv, int* __restrict__ Bsum) {
    __shared__ _Float16 XOUT[2][64][72];
    __shared__ int s[256];
    const int b = blockIdx.x;
    const int t = threadIdx.x;
    if (b < NPRE_B) {
        // error-free fp16 split: x = xh + xr, W = Wh + Wr; acc += xh*Wh + xr*Wh + xh*Wr
        const int n0 = b * 64;
        const int w = t >> 6;
        const int lane = t & 63;
        const int r15 = lane & 15, blk = lane >> 4;
        const int nodeRow = n0 + w * 16 + r15;
        const bool rowOK = nodeRow < NN;
        f4 accA[4], accB[4];
#pragma unroll
        for (int n = 0; n < 4; ++n) {
            accA[n] = (f4){0.f, 0.f, 0.f, 0.f};
            accB[n] = (f4){0.f, 0.f, 0.f, 0.f};
        }
#pragma unroll
        for (int kk = 0; kk < 4; ++kk) {
            f4 x0 = (f4){0.f, 0.f, 0.f, 0.f}, x1 = x0;
            if (rowOK) {
                const f4* xp = (const f4*)(x + (size_t)nodeRow * 128 + kk * 32 + blk * 8);
                x0 = xp[0];
                x1 = xp[1];
            }
            h8 xh, xr;
#pragma unroll
            for (int n = 0; n < 4; ++n) {
                xh[n] = (_Float16)x0[n];
                xr[n] = (_Float16)(x0[n] - (float)xh[n]);
                xh[4 + n] = (_Float16)x1[n];
                xr[4 + n] = (_Float16)(x1[n] - (float)xh[4 + n]);
            }
#pragma unroll
            for (int ncol = 0; ncol < 4; ++ncol) {
                const int nA = ncol * 16 + r15;
                const int koff = kk * 32 + blk * 8;
                h8 whA = *(const h8*)(W1th + nA * 128 + koff);
                h8 wrA = *(const h8*)(W1tr + nA * 128 + koff);
                accA[ncol] = __builtin_amdgcn_mfma_f32_16x16x32_f16(xh, whA, accA[ncol], 0, 0, 0);
                accA[ncol] = __builtin_amdgcn_mfma_f32_16x16x32_f16(xr, whA, accA[ncol], 0, 0, 0);
                accA[ncol] = __builtin_amdgcn_mfma_f32_16x16x32_f16(xh, wrA, accA[ncol], 0, 0, 0);
                h8 whB = *(const h8*)(W1th + (64 + nA) * 128 + koff);
                h8 wrB = *(const h8*)(W1tr + (64 + nA) * 128 + koff);
                accB[ncol] = __builtin_amdgcn_mfma_f32_16x16x32_f16(xh, whB, accB[ncol], 0, 0, 0);
                accB[ncol] = __builtin_amdgcn_mfma_f32_16x16x32_f16(xr, whB, accB[ncol], 0, 0, 0);
                accB[ncol] = __builtin_amdgcn_mfma_f32_16x16x32_f16(xh, wrB, accB[ncol], 0, 0, 0);
            }
        }
        // repack via LDS (D layout: row = blk*4+reg, col = ncol*16+r15)
#pragma unroll
        for (int ncol = 0; ncol < 4; ++ncol)
#pragma unroll
            for (int reg = 0; reg < 4; ++reg) {
                const int row = w * 16 + blk * 4 + reg;
                XOUT[0][row][ncol * 16 + r15] = (_Float16)accA[ncol][reg];
                XOUT[1][row][ncol * 16 + r15] = (_Float16)accB[ncol][reg];
            }
        __syncthreads();
#pragma unroll
        for (int u = 0; u < 4; ++u) {
            const int idx = t + 256 * u;        // 0..1023
            const int mat = idx >> 9;
            const int row = (idx >> 3) & 63;
            const int c8 = idx & 7;
            const int grow = n0 + row;
            if (grow < NN) {
                _Float16* dst = (mat ? XB : XA) + (size_t)grow * 64 + c8 * 8;
                *(h8*)dst = *(const h8*)&XOUT[mat][row][c8 * 8];
            }
        }
    } else {
        // ---- zero a slice of sums, then local exclusive scan of C ----
        const int sb = b - NPRE_B;
        {
            f4* sz = (f4*)sums + (size_t)sb * 4096;
            const int cnt4 = min(4096, 1600000 - sb * 4096);
            for (int u = t; u < cnt4; u += 256) sz[u] = (f4){0.f, 0.f, 0.f, 0.f};
        }
        const int gid = sb * 256 + t;
        const int v = (gid < NN) ? C[gid] : 0;
        s[t] = v;
        __syncthreads();
        for (int off = 1; off < 256; off <<= 1) {
            int add = (t >= off) ? s[t - off] : 0;
            __syncthreads();
            s[t] += add;
            __syncthreads();
        }
        if (gid < NN) offv[gid] = s[t] - v;
        if (t == 255) Bsum[sb] = s[255];
    }
}

// ==== scatter (fused Bsum scan, ILP4): PL4[p] = {i, k, attr_f16x2, j} ====
__global__ __launch_bounds__(256) void k_scatter(
    const int* __restrict__ ti, const int* __restrict__ tj, const int* __restrict__ tk,
    const float* __restrict__ attr,
    const int* __restrict__ Bsum, int* __restrict__ offv,
    int4* __restrict__ PL4) {
    __shared__ int BpreS[NBLK_SCAN];
    const int t = threadIdx.x;
    const int w = t >> 6, lane = t & 63;
    if (w == 0) {
        int carry = 0;
        for (int base = 0; base < NBLK_SCAN; base += 64) {
            const int idx = base + lane;
            const int orig = (idx < NBLK_SCAN) ? Bsum[idx] : 0;
            int v = orig;
#pragma unroll
            for (int off = 1; off < 64; off <<= 1) {
                int u = __shfl_up(v, off, 64);
                if (lane >= off) v += u;
            }
            if (idx < NBLK_SCAN) BpreS[idx] = carry + v - orig;
            carry += __shfl(v, 63, 64);
        }
    }
    __syncthreads();
    const int base = blockIdx.x * 1024 + t;
#pragma unroll
    for (int u = 0; u < 4; ++u) {
        const int e = base + u * 256;
        if (e < NE) {
            const int j = tj[e];
            const f2 at = ((const f2*)attr)[e];
            const int p = BpreS[j >> 8] + atomicAdd(&offv[j], 1);
            PL4[p] = (int4){ti[e], tk[e], (int)pack_f16x2(at[0], at[1]), j};
        }
    }
}

// ==== edge kernel: h1 (VALU) -> h2 (MFMA fp16) -> segment-reduce by j ====
__global__ __launch_bounds__(256, 8) void k_edge(
    const int4* __restrict__ PL4,
    const _Float16* __restrict__ XA, const _Float16* __restrict__ XB,
    const _Float16* __restrict__ W1C16,
    const _Float16* __restrict__ W2t, const float* __restrict__ b2,
    float* __restrict__ sums, int blk0) {
    __shared__ __align__(16) char SBraw[64 * 68 * 4];  // M[64][68] f32; H1h[64][72] fp16
    __shared__ int JL[64];
    __shared__ int RS[66];
    __shared__ int nruns_s;

    _Float16* H1h = (_Float16*)SBraw;   // [64][72]
    float* M = (float*)SBraw;           // [64][68]

    const int t = threadIdx.x;
    const int w = t >> 6;
    const int lane = t & 63;
    const int EB = (blk0 + blockIdx.x) * 64;

    // ---- phase 1: h1 = silu(XA[i] + XB[k] + attr@W1c + b1) fp16, 4 thr/edge ----
    {
        const int el = t >> 2;
        const int q = t & 3;
        const int4 pl = PL4[EB + el];
        const int i = pl.x;
        const int k = pl.y;
        if (q == 0) JL[el] = pl.w;
        const unsigned atp = (unsigned)pl.z;
        const float at0 = (float)__builtin_bit_cast(_Float16, (unsigned short)(atp & 0xffffu));
        const float at1 = (float)__builtin_bit_cast(_Float16, (unsigned short)(atp >> 16));
        const _Float16* xa = XA + (size_t)i * 64 + q * 16;
        const _Float16* xb = XB + (size_t)k * 64 + q * 16;
        h8 va0 = ((const h8*)xa)[0], va1 = ((const h8*)xa)[1];
        h8 vb0 = ((const h8*)xb)[0], vb1 = ((const h8*)xb)[1];
        const _Float16* c0p = W1C16 + q * 16;
        const _Float16* c1p = W1C16 + 64 + q * 16;
        const _Float16* bqp = W1C16 + 128 + q * 16;
        h8 c00 = ((const h8*)c0p)[0], c01 = ((const h8*)c0p)[1];
        h8 c10 = ((const h8*)c1p)[0], c11 = ((const h8*)c1p)[1];
        h8 bq0 = ((const h8*)bqp)[0], bq1 = ((const h8*)bqp)[1];
        _Float16 hrow[16];
#pragma unroll
        for (int n = 0; n < 8; ++n) {
            float pre0 = (float)va0[n] + (float)vb0[n]
                       + at0 * (float)c00[n] + at1 * (float)c10[n] + (float)bq0[n];
            float pre1 = (float)va1[n] + (float)vb1[n]
                       + at0 * (float)c01[n] + at1 * (float)c11[n] + (float)bq1[n];
            hrow[n] = (_Float16)silu(pre0);
            hrow[8 + n] = (_Float16)silu(pre1);
        }
        h8 s0, s1;
#pragma unroll
        for (int n = 0; n < 8; ++n) { s0[n] = hrow[n]; s1[n] = hrow[8 + n]; }
        _Float16* row = H1h + el * 72 + q * 16;
        ((h8*)row)[0] = s0;
        ((h8*)row)[1] = s1;
    }
    __syncthreads();

    // ---- phase 2: H2 = silu(H1 @ W2 + b2) via mfma_f32_16x16x32_f16 ----
    const int r15 = lane & 15;
    const int blk = lane >> 4;
    float h2v[16];
    {
        const _Float16* H1w = H1h + (w * 16) * 72;
        h8 a0 = *(const h8*)(H1w + r15 * 72 + blk * 8);
        h8 a1 = *(const h8*)(H1w + r15 * 72 + 32 + blk * 8);
#pragma unroll
        for (int ncol = 0; ncol < 4; ++ncol) {
            const _Float16* Wn = W2t + (ncol * 16 + r15) * 64 + blk * 8;
            h8 b0 = *(const h8*)(Wn);
            h8 b1v = *(const h8*)(Wn + 32);
            const float bc = b2[ncol * 16 + r15];
            f4 acc = {bc, bc, bc, bc};
            acc = __builtin_amdgcn_mfma_f32_16x16x32_f16(a0, b0, acc, 0, 0, 0);
            acc = __builtin_amdgcn_mfma_f32_16x16x32_f16(a1, b1v, acc, 0, 0, 0);
#pragma unroll
            for (int reg = 0; reg < 4; ++reg) h2v[ncol * 4 + reg] = silu(acc[reg]);
        }
    }
    __syncthreads();

    // ---- phase 3: write H2 to M (f32); wave 0 finds run heads over sorted JL ----
#pragma unroll
    for (int ncol = 0; ncol < 4; ++ncol)
#pragma unroll
        for (int reg = 0; reg < 4; ++reg)
            M[(w * 16 + blk * 4 + reg) * 68 + ncol * 16 + r15] = h2v[ncol * 4 + reg];
    if (t < 64) {
        bool head = (t == 0) || (JL[t] != JL[t - 1]);
        unsigned long long mask = __ballot(head);
        if (head) {
            int rank = __popcll(mask & ((1ull << t) - 1ull));
            RS[rank] = t;
        }
        if (t == 0) {
            int nr = __popcll(mask);
            nruns_s = nr;
            RS[nr] = 64;
        }
    }
    __syncthreads();

    // ---- phase 4: per-run column reduce + one 64-wide atomic row per run ----
    {
        const int col = t & 63;
        const int q4 = t >> 6;
        const int nr = nruns_s;
        for (int rid = q4; rid < nr; rid += 4) {
            const int s0 = RS[rid];
            const int s1 = RS[rid + 1];
            float a = 0.f;
            for (int rr = s0; rr < s1; ++rr) a += M[rr * 68 + col];
            atomicAdd(&sums[(size_t)JL[s0] * 64 + col], a);
        }
    }
}

// ==== out = (sums/max(cnt,1)) @ W3W + [cnt>0]*bout (32 nodes/block) ====
__global__ __launch_bounds__(256) void k_out(const float* __restrict__ sums,
                                             const int* __restrict__ C,
                                             const float* __restrict__ W3W,
                                             float* __restrict__ out) {
    __shared__ float S[32][64];
    __shared__ float bs[32];
    const int t = threadIdx.x;
    const int n0 = blockIdx.x * 32;
    const f4* ss = (const f4*)(sums + (size_t)n0 * 64);
    f4* Ss = (f4*)&S[0][0];
#pragma unroll
    for (int q = 0; q < 2; ++q) {
        const int fidx = t + 256 * q;
        const int row = fidx >> 4;
        const int cn = C[n0 + row];
        const float sc = (cn > 0) ? 1.0f / (float)cn : 0.0f;
        f4 v = ss[fidx];
#pragma unroll
        for (int n = 0; n < 4; ++n) v[n] *= sc;
        Ss[fidx] = v;
    }
    if (t < 32) bs[t] = (C[n0 + t] > 0) ? 1.0f : 0.0f;
    __syncthreads();
    const int w = t >> 6, lane = t & 63;
    const float* bout = W3W + 64 * 128;
    float a0[8], a1[8];
#pragma unroll
    for (int m = 0; m < 8; ++m) { a0[m] = 0.f; a1[m] = 0.f; }
    for (int d = 0; d < 64; ++d) {
        float w0 = W3W[d * 128 + lane];
        float w1 = W3W[d * 128 + 64 + lane];
#pragma unroll
        for (int m = 0; m < 8; ++m) {
            float sv = S[w * 8 + m][d];
            a0[m] += sv * w0;
            a1[m] += sv * w1;
        }
    }
    const float bo0 = bout[lane], bo1 = bout[64 + lane];
#pragma unroll
    for (int m = 0; m < 8; ++m) {
        const int node = n0 + w * 8 + m;
        const float b = bs[w * 8 + m];
        out[(size_t)node * 128 + lane] = a0[m] + b * bo0;
        out[(size_t)node * 128 + 64 + lane] = a1[m] + b * bo1;
    }
}

extern "C" void kernel_launch(void* const* d_in, const int* in_sizes, int n_in,
                              void* d_out, int out_size, void* d_ws, size_t ws_size,
                              hipStream_t stream) {
    const float* x    = (const float*)d_in[0];
    const int*   idx  = (const int*)d_in[1];
    const float* attr = (const float*)d_in[2];
    const float* W1   = (const float*)d_in[3];
    const float* b1   = (const float*)d_in[4];
    const float* W2   = (const float*)d_in[5];
    const float* b2   = (const float*)d_in[6];
    const float* W3   = (const float*)d_in[7];
    const float* b3   = (const float*)d_in[8];
    const float* Wout = (const float*)d_in[9];
    float* out = (float*)d_out;

    const int* ti = idx;
    const int* tj = idx + NE;
    const int* tk = idx + 2 * NE;

    float* ws   = (float*)d_ws;
    float* sums = ws + O_SUMS;
    int*   C    = (int*)(ws + O_CNT);
    int*   offv = (int*)(ws + O_OFF);
    int*   Bsum = (int*)(ws + O_BSUM);
    int4*  PL4  = (int4*)(ws + O_PL);
    _Float16* XA  = (_Float16*)(ws + O_XA);
    _Float16* XB  = (_Float16*)(ws + O_XB);
    float* W3W  = ws + O_W3W;
    _Float16* W2t   = (_Float16*)(ws + O_W2T);
    _Float16* W1th  = (_Float16*)(ws + O_W1TH);
    _Float16* W1tr  = (_Float16*)(ws + O_W1TR);
    _Float16* W1C16 = (_Float16*)(ws + O_W1C16);

    hipMemsetAsync(C, 0, (size_t)NN * sizeof(int), stream);

    hipLaunchKernelGGL(k_prep0,   dim3(PREP0_B), dim3(256), 0, stream,
                       tj, W1, b1, W2, W3, b3, Wout, C, W3W, W2t, W1th, W1tr, W1C16);
    hipLaunchKernelGGL(k_mid,     dim3(MID_B), dim3(256), 0, stream,
                       x, W1th, W1tr, XA, XB, C, sums, offv, Bsum);
    hipLaunchKernelGGL(k_scatter, dim3(SCAT_B), dim3(256), 0, stream,
                       ti, tj, tk, attr, Bsum, offv, PL4);
    hipLaunchKernelGGL(k_edge,    dim3(EDGE_B1), dim3(256), 0, stream,
                       PL4, XA, XB, W1C16, W2t, b2, sums, 0);
    hipLaunchKernelGGL(k_edge,    dim3(EDGE_B2), dim3(256), 0, stream,
                       PL4, XA, XB, W1C16, W2t, b2, sums, EDGE_B1);
    hipLaunchKernelGGL(k_out,     dim3(3125), dim3(256), 0, stream, sums, C, W3W, out);
}